// Round 8
// baseline (184.460 us; speedup 1.0000x reference)
//
#include <hip/hip_runtime.h>
#include <math.h>

#define BATCH   64
#define NFEAT   256
#define GS      4
#define NG      64
#define WH      3136            // 56*56
#define PLANEQ  784             // WH/4; = 3*256 + 16
#define NTOT    (BATCH*WH)
#define EPSV    1e-3

typedef float vf4 __attribute__((ext_vector_type(4)));
typedef unsigned long long u64;

#define AL64(p)    __hip_atomic_load((p), __ATOMIC_RELAXED, __HIP_MEMORY_SCOPE_AGENT)
#define AX64(p,v)  __hip_atomic_exchange((p), (v), __ATOMIC_RELAXED, __HIP_MEMORY_SCOPE_AGENT)
#define ALI(p)     __hip_atomic_load((p), __ATOMIC_RELAXED, __HIP_MEMORY_SCOPE_AGENT)
#define AXI(p,v)   __hip_atomic_exchange((p), (v), __ATOMIC_RELAXED, __HIP_MEMORY_SCOPE_AGENT)
#define AAI(p,v)   __hip_atomic_fetch_add((p), (v), __ATOMIC_RELAXED, __HIP_MEMORY_SCOPE_AGENT)

__device__ inline u64 pack2(float a, float b) {
    union { float f[2]; u64 u; } t; t.f[0] = a; t.f[1] = b; return t.u;
}
__device__ inline void unpack2(u64 u, float& a, float& b) {
    union { u64 u; float f[2]; } t; t.u = u; a = t.f[0]; b = t.f[1];
}

// Lane-serial 4x4 Jacobi from double sums acc[14]; writes wo[0..15]=W,
// wo[16..19]=-W m.
__device__ void solve_group(const double* acc, float* wo) {
    const double n = (double)NTOT;
    double m[4];
    #pragma unroll
    for (int i = 0; i < 4; ++i) m[i] = acc[i] / n;

    const int pi[10] = {0,0,0,0,1,1,1,2,2,3};
    const int pj[10] = {0,1,2,3,1,2,3,2,3,3};

    double A[4][4];
    #pragma unroll
    for (int t = 0; t < 10; ++t) {
        double cov = acc[4 + t] - n * m[pi[t]] * m[pj[t]];
        double v = (1.0 - EPSV) * cov + ((pi[t] == pj[t]) ? EPSV : 0.0);
        A[pi[t]][pj[t]] = v;
        A[pj[t]][pi[t]] = v;
    }

    double V[4][4] = {{1,0,0,0},{0,1,0,0},{0,0,1,0},{0,0,0,1}};
    const double tr = A[0][0] + A[1][1] + A[2][2] + A[3][3];
    const double tol = 1e-26 * tr * tr + 1e-300;
    const int rp[6] = {0,0,0,1,1,2};
    const int rq[6] = {1,2,3,2,3,3};

    for (int sweep = 0; sweep < 10; ++sweep) {
        double off = 0.0;
        #pragma unroll
        for (int t = 0; t < 6; ++t) off += A[rp[t]][rq[t]] * A[rp[t]][rq[t]];
        if (off < tol) break;
        #pragma unroll
        for (int t = 0; t < 6; ++t) {
            const int p = rp[t], q = rq[t];
            double apq = A[p][q];
            if (apq * apq < 1e-60) continue;
            double theta = (A[q][q] - A[p][p]) / (2.0 * apq);
            double tt = ((theta >= 0.0) ? 1.0 : -1.0) /
                        (fabs(theta) + sqrt(theta * theta + 1.0));
            double c = 1.0 / sqrt(tt * tt + 1.0);
            double s = tt * c;
            #pragma unroll
            for (int k = 0; k < 4; ++k) {
                double akp = A[k][p], akq = A[k][q];
                A[k][p] = c * akp - s * akq;
                A[k][q] = s * akp + c * akq;
            }
            #pragma unroll
            for (int k = 0; k < 4; ++k) {
                double apk = A[p][k], aqk = A[q][k];
                A[p][k] = c * apk - s * aqk;
                A[q][k] = s * apk + c * aqk;
            }
            #pragma unroll
            for (int k = 0; k < 4; ++k) {
                double vkp = V[k][p], vkq = V[k][q];
                V[k][p] = c * vkp - s * vkq;
                V[k][q] = s * vkp + c * vkq;
            }
        }
    }

    double isq[4];
    #pragma unroll
    for (int k = 0; k < 4; ++k) isq[k] = 1.0 / sqrt(A[k][k] + EPSV);

    double Wd[4][4];
    #pragma unroll
    for (int i = 0; i < 4; ++i) {
        #pragma unroll
        for (int j = 0; j < 4; ++j) {
            double w = 0.0;
            #pragma unroll
            for (int k = 0; k < 4; ++k) w += V[i][k] * V[j][k] * isq[k];
            Wd[i][j] = w;
            wo[i * 4 + j] = (float)w;
        }
    }
    #pragma unroll
    for (int i = 0; i < 4; ++i) {
        double wmI = Wd[i][0]*m[0] + Wd[i][1]*m[1] + Wd[i][2]*m[2] + Wd[i][3]*m[3];
        wo[16 + i] = (float)(-wmI);
    }
}

// ============ Single-pass kernel: block (g,b) holds its tile in regs =======
// blk = g*64 + b  (group-major: a group's 64 blocks have contiguous ids).
// Phase 1: load tile (16 vf4/thread), 14 partial sums, publish as 7 u64
//          device-scope atomicExch. atomicAdd arrival counter.
// Phase 2: 64th arriver: gather 64 records (atomic loads), butterfly,
//          lane-0 Jacobi, publish W (10 u64) + flag. Others spin (timeout).
// Phase 3: apply from registers, NT-store out.
__global__ __launch_bounds__(256, 2) void wh_onepass(const float* __restrict__ x,
                                                     u64* __restrict__ partials,
                                                     u64* __restrict__ wst,
                                                     int* __restrict__ cnt,
                                                     int* __restrict__ flag,
                                                     float* __restrict__ out) {
    const int g   = blockIdx.x >> 6;
    const int b   = blockIdx.x & 63;
    const int tid = threadIdx.x;

    const size_t off = (size_t)b * ((size_t)NFEAT * WH) + (size_t)g * (GS * WH);
    const vf4* __restrict__ xin = (const vf4*)(x + off);

    const bool tail = (tid < PLANEQ - 768);
    const int  qt   = 768 + (tid & 15);          // in-bounds clamp

    // ---- Phase 1a: load tile into registers: d[c][r], r=0..2 strided, 3=tail
    vf4 d[4][4];
    #pragma unroll
    for (int c = 0; c < 4; ++c) {
        #pragma unroll
        for (int r = 0; r < 3; ++r) d[c][r] = xin[c * PLANEQ + tid + 256 * r];
    }
    #pragma unroll
    for (int c = 0; c < 4; ++c) {
        vf4 t = xin[c * PLANEQ + qt];
        if (!tail) t = (vf4){0.f, 0.f, 0.f, 0.f};
        d[c][3] = t;
    }

    // ---- Phase 1b: 14 partial sums ----
    float s0=0.f,s1=0.f,s2=0.f,s3=0.f;
    float p0=0.f,p1=0.f,p2=0.f,p3=0.f,p4=0.f,p5=0.f,p6=0.f,p7=0.f,p8=0.f,p9=0.f;
    #pragma unroll
    for (int r = 0; r < 4; ++r) {
        #pragma unroll
        for (int k = 0; k < 4; ++k) {
            float A = d[0][r][k], B = d[1][r][k], C = d[2][r][k], D = d[3][r][k];
            s0 += A; s1 += B; s2 += C; s3 += D;
            p0 = fmaf(A, A, p0);  p1 = fmaf(A, B, p1);
            p2 = fmaf(A, C, p2);  p3 = fmaf(A, D, p3);
            p4 = fmaf(B, B, p4);  p5 = fmaf(B, C, p5);
            p6 = fmaf(B, D, p6);  p7 = fmaf(C, C, p7);
            p8 = fmaf(C, D, p8);  p9 = fmaf(D, D, p9);
        }
    }

    float vals[14] = {s0,s1,s2,s3,p0,p1,p2,p3,p4,p5,p6,p7,p8,p9};
    #pragma unroll
    for (int q = 0; q < 14; ++q) {
        float v = vals[q];
        #pragma unroll
        for (int o = 32; o > 0; o >>= 1) v += __shfl_down(v, o, 64);
        vals[q] = v;
    }

    __shared__ float lds[4][14];
    __shared__ float sfin[14];
    __shared__ float sW[20];
    __shared__ int role;
    const int wave = tid >> 6;
    const int lane = tid & 63;
    if (lane == 0) {
        #pragma unroll
        for (int q = 0; q < 14; ++q) lds[wave][q] = vals[q];
    }
    __syncthreads();
    if (tid < 14) sfin[tid] = lds[0][tid] + lds[1][tid] + lds[2][tid] + lds[3][tid];
    __syncthreads();

    // ---- publish partials (device-scope atomics, no fence) ----
    if (tid < 7)
        AX64(&partials[(size_t)blockIdx.x * 8 + tid], pack2(sfin[2*tid], sfin[2*tid+1]));
    __syncthreads();   // drains vmcnt: exchanges complete before arrival
    if (tid == 0) role = (AAI(&cnt[g], 1) == BATCH - 1) ? 1 : 0;
    __syncthreads();

    if (role) {
        // ---- solver: gather 64 records, butterfly, lane-0 Jacobi ----
        double acc[14];
        if (tid < 64) {
            u64 r[7];
            #pragma unroll
            for (int i = 0; i < 7; ++i)
                r[i] = AL64(&partials[(size_t)(g * BATCH + tid) * 8 + i]);
            #pragma unroll
            for (int i = 0; i < 7; ++i) {
                float a, bb;
                unpack2(r[i], a, bb);
                acc[2*i] = (double)a; acc[2*i+1] = (double)bb;
            }
            #pragma unroll
            for (int o = 32; o > 0; o >>= 1) {
                #pragma unroll
                for (int q = 0; q < 14; ++q) acc[q] += __shfl_xor(acc[q], o, 64);
            }
        }
        if (tid == 0) {
            float wo[20];
            solve_group(acc, wo);
            #pragma unroll
            for (int q = 0; q < 20; ++q) sW[q] = wo[q];
        }
        __syncthreads();
        if (tid < 10)
            AX64(&wst[(size_t)g * 16 + tid], pack2(sW[2*tid], sW[2*tid+1]));
        __syncthreads();   // drain: W published before flag
        if (tid == 0) AXI(&flag[g], 1);
    } else {
        if (tid == 0) {
            long long t0 = clock64();
            while (ALI(&flag[g]) == 0) {
                if (clock64() - t0 > (1LL << 28)) break;   // ~0.1 s safety
                __builtin_amdgcn_s_sleep(8);
            }
        }
        __syncthreads();
        if (tid < 10) {
            u64 v = AL64(&wst[(size_t)g * 16 + tid]);
            float a, bb;
            unpack2(v, a, bb);
            sW[2*tid] = a; sW[2*tid+1] = bb;
        }
        __syncthreads();
    }

    // ---- Phase 3: apply from registers ----
    float W[4][4], nwm[4];
    #pragma unroll
    for (int i = 0; i < 4; ++i) {
        #pragma unroll
        for (int j = 0; j < 4; ++j) W[i][j] = sW[i * 4 + j];
        nwm[i] = sW[16 + i];
    }

    vf4* __restrict__ o = (vf4*)(out + off);
    #pragma unroll
    for (int i = 0; i < 4; ++i) {
        #pragma unroll
        for (int r = 0; r < 3; ++r) {
            vf4 rr;
            #pragma unroll
            for (int k = 0; k < 4; ++k) {
                rr[k] = fmaf(W[i][0], d[0][r][k],
                        fmaf(W[i][1], d[1][r][k],
                        fmaf(W[i][2], d[2][r][k],
                        fmaf(W[i][3], d[3][r][k], nwm[i]))));
            }
            __builtin_nontemporal_store(rr, &o[i * PLANEQ + tid + 256 * r]);
        }
        if (tail) {
            vf4 rr;
            #pragma unroll
            for (int k = 0; k < 4; ++k) {
                rr[k] = fmaf(W[i][0], d[0][3][k],
                        fmaf(W[i][1], d[1][3][k],
                        fmaf(W[i][2], d[2][3][k],
                        fmaf(W[i][3], d[3][3][k], nwm[i]))));
            }
            __builtin_nontemporal_store(rr, &o[i * PLANEQ + qt]);
        }
    }
}

extern "C" void kernel_launch(void* const* d_in, const int* in_sizes, int n_in,
                              void* d_out, int out_size, void* d_ws, size_t ws_size,
                              hipStream_t stream) {
    const float* x = (const float*)d_in[0];
    float* out = (float*)d_out;

    // ws layout (u64-aligned): partials[4096*8 u64] | wst[64*16 u64] | cnt[64] | flag[64]
    u64* partials = (u64*)d_ws;                       // 256 KiB
    u64* wst      = partials + (size_t)BATCH * NG * 8;  // 8 KiB
    int* cnt      = (int*)(wst + (size_t)NG * 16);
    int* flag     = cnt + NG;

    hipMemsetAsync(cnt, 0, 2 * NG * sizeof(int), stream);
    wh_onepass<<<BATCH * NG, 256, 0, stream>>>(x, partials, wst, cnt, flag, out);
}

// Round 9
// 113.843 us; speedup vs baseline: 1.6203x; 1.6203x over previous
//
#include <hip/hip_runtime.h>
#include <math.h>

#define BATCH   64
#define NFEAT   256
#define GS      4
#define NG      64
#define WH      3136            // 56*56
#define PLANEQ  784             // WH/4; = 3*256 + 16
#define NTOT    (BATCH*WH)
#define EPSV    1e-3
#define PREC    16              // padded floats per partial record

typedef float vf4 __attribute__((ext_vector_type(4)));

// ---------------- Stage 1: partial sums, 2 contiguous groups per block ----
// Block B (0..2047): b = (2B)>>6, g0 = (2B)&63 (even), covers g0 and g0+1.
// 100 KB contiguous stream per block. Writes 2 records of 14 sums.
__device__ __forceinline__ void reduce_tile(const vf4* __restrict__ xin,
                                            int tid, float* vals) {
    float s0=0.f,s1=0.f,s2=0.f,s3=0.f;
    float p0=0.f,p1=0.f,p2=0.f,p3=0.f,p4=0.f,p5=0.f,p6=0.f,p7=0.f,p8=0.f,p9=0.f;

    vf4 a0 = xin[tid];             vf4 a1 = xin[tid + 256];             vf4 a2 = xin[tid + 512];
    vf4 b0 = xin[PLANEQ + tid];    vf4 b1 = xin[PLANEQ + tid + 256];    vf4 b2 = xin[PLANEQ + tid + 512];
    vf4 c0 = xin[2*PLANEQ + tid];  vf4 c1 = xin[2*PLANEQ + tid + 256];  vf4 c2 = xin[2*PLANEQ + tid + 512];
    vf4 d0 = xin[3*PLANEQ + tid];  vf4 d1 = xin[3*PLANEQ + tid + 256];  vf4 d2 = xin[3*PLANEQ + tid + 512];

#define ACC4(va, vb, vc, vd)                                         \
    {                                                                \
        _Pragma("unroll")                                            \
        for (int k = 0; k < 4; ++k) {                                \
            float A = (va)[k], B = (vb)[k], C = (vc)[k], D = (vd)[k];\
            s0 += A; s1 += B; s2 += C; s3 += D;                      \
            p0 = fmaf(A, A, p0);  p1 = fmaf(A, B, p1);               \
            p2 = fmaf(A, C, p2);  p3 = fmaf(A, D, p3);               \
            p4 = fmaf(B, B, p4);  p5 = fmaf(B, C, p5);               \
            p6 = fmaf(B, D, p6);  p7 = fmaf(C, C, p7);               \
            p8 = fmaf(C, D, p8);  p9 = fmaf(D, D, p9);               \
        }                                                            \
    }
    ACC4(a0, b0, c0, d0);
    ACC4(a1, b1, c1, d1);
    ACC4(a2, b2, c2, d2);
    if (tid < PLANEQ - 768) {
        vf4 at = xin[768 + tid];
        vf4 bt = xin[PLANEQ + 768 + tid];
        vf4 ct = xin[2*PLANEQ + 768 + tid];
        vf4 dt = xin[3*PLANEQ + 768 + tid];
        ACC4(at, bt, ct, dt);
    }
#undef ACC4
    vals[0]=s0; vals[1]=s1; vals[2]=s2; vals[3]=s3;
    vals[4]=p0; vals[5]=p1; vals[6]=p2; vals[7]=p3; vals[8]=p4;
    vals[9]=p5; vals[10]=p6; vals[11]=p7; vals[12]=p8; vals[13]=p9;
}

__global__ __launch_bounds__(256) void wh_reduce(const float* __restrict__ x,
                                                 float* __restrict__ partials) {
    const int idx0 = blockIdx.x << 1;          // even tile index
    const int b  = idx0 >> 6;
    const int g0 = idx0 & 63;
    const int tid = threadIdx.x;

    const vf4* __restrict__ x0 =
        (const vf4*)(x + (size_t)b * ((size_t)NFEAT * WH) + (size_t)g0 * (GS * WH));
    const vf4* __restrict__ x1 = x0 + GS * PLANEQ;

    float vv[28];
    reduce_tile(x0, tid, vv);
    reduce_tile(x1, tid, vv + 14);

    #pragma unroll
    for (int q = 0; q < 28; ++q) {
        float v = vv[q];
        #pragma unroll
        for (int off = 32; off > 0; off >>= 1) v += __shfl_down(v, off, 64);
        vv[q] = v;
    }

    __shared__ float lds[4][28];
    const int wave = tid >> 6;
    const int lane = tid & 63;
    if (lane == 0) {
        #pragma unroll
        for (int q = 0; q < 28; ++q) lds[wave][q] = vv[q];
    }
    __syncthreads();
    if (tid < 28) {
        float v = lds[0][tid] + lds[1][tid] + lds[2][tid] + lds[3][tid];
        const int s = tid / 14, q = tid - s * 14;
        partials[((size_t)((g0 + s) * BATCH + b)) * PREC + q] = v;
    }
}

// ---------------- Stage 2: per-group eigen solve (unchanged R5) ----------
__global__ __launch_bounds__(64) void wh_eigen(const float* __restrict__ partials,
                                               float* __restrict__ wm) {
    const int g = blockIdx.x;
    const int b = threadIdx.x;

    const float* base = partials + ((size_t)(g * BATCH + b)) * PREC;
    double acc[14];
    #pragma unroll
    for (int q = 0; q < 14; ++q) acc[q] = (double)base[q];

    #pragma unroll
    for (int off = 32; off > 0; off >>= 1) {
        #pragma unroll
        for (int q = 0; q < 14; ++q) acc[q] += __shfl_xor(acc[q], off, 64);
    }

    if (b != 0) return;

    const double n = (double)NTOT;
    double m[4];
    #pragma unroll
    for (int i = 0; i < 4; ++i) m[i] = acc[i] / n;

    const int pi[10] = {0,0,0,0,1,1,1,2,2,3};
    const int pj[10] = {0,1,2,3,1,2,3,2,3,3};

    double A[4][4];
    #pragma unroll
    for (int t = 0; t < 10; ++t) {
        double cov = acc[4 + t] - n * m[pi[t]] * m[pj[t]];
        double v = (1.0 - EPSV) * cov + ((pi[t] == pj[t]) ? EPSV : 0.0);
        A[pi[t]][pj[t]] = v;
        A[pj[t]][pi[t]] = v;
    }

    double V[4][4] = {{1,0,0,0},{0,1,0,0},{0,0,1,0},{0,0,0,1}};
    const double tr = A[0][0] + A[1][1] + A[2][2] + A[3][3];
    const double tol = 1e-26 * tr * tr + 1e-300;
    const int rp[6] = {0,0,0,1,1,2};
    const int rq[6] = {1,2,3,2,3,3};

    for (int sweep = 0; sweep < 10; ++sweep) {
        double off = 0.0;
        #pragma unroll
        for (int t = 0; t < 6; ++t) off += A[rp[t]][rq[t]] * A[rp[t]][rq[t]];
        if (off < tol) break;

        #pragma unroll
        for (int t = 0; t < 6; ++t) {
            const int p = rp[t], q = rq[t];
            double apq = A[p][q];
            if (apq * apq < 1e-60) continue;
            double theta = (A[q][q] - A[p][p]) / (2.0 * apq);
            double tt = ((theta >= 0.0) ? 1.0 : -1.0) /
                        (fabs(theta) + sqrt(theta * theta + 1.0));
            double c = 1.0 / sqrt(tt * tt + 1.0);
            double s = tt * c;
            #pragma unroll
            for (int k = 0; k < 4; ++k) {
                double akp = A[k][p], akq = A[k][q];
                A[k][p] = c * akp - s * akq;
                A[k][q] = s * akp + c * akq;
            }
            #pragma unroll
            for (int k = 0; k < 4; ++k) {
                double apk = A[p][k], aqk = A[q][k];
                A[p][k] = c * apk - s * aqk;
                A[q][k] = s * apk + c * aqk;
            }
            #pragma unroll
            for (int k = 0; k < 4; ++k) {
                double vkp = V[k][p], vkq = V[k][q];
                V[k][p] = c * vkp - s * vkq;
                V[k][q] = s * vkp + c * vkq;
            }
        }
    }

    double isq[4];
    #pragma unroll
    for (int k = 0; k < 4; ++k) isq[k] = 1.0 / sqrt(A[k][k] + EPSV);

    float* wo = wm + g * 24;
    double Wd[4][4];
    #pragma unroll
    for (int i = 0; i < 4; ++i) {
        #pragma unroll
        for (int j = 0; j < 4; ++j) {
            double w = 0.0;
            #pragma unroll
            for (int k = 0; k < 4; ++k) w += V[i][k] * V[j][k] * isq[k];
            Wd[i][j] = w;
            wo[i * 4 + j] = (float)w;
        }
    }
    #pragma unroll
    for (int i = 0; i < 4; ++i) {
        double wmI = Wd[i][0]*m[0] + Wd[i][1]*m[1] + Wd[i][2]*m[2] + Wd[i][3]*m[3];
        wo[16 + i] = (float)(-wmI);
        wo[20 + i] = (float)m[i];
    }
}

// ---------------- Stage 3: apply, 2 contiguous groups per block ----------
// Plain loads on x (R7 showed NT loads regress), NT stores on out.
__global__ __launch_bounds__(256) void wh_apply(const float* __restrict__ x,
                                                const float* __restrict__ wm,
                                                float* __restrict__ out) {
    const int idx0 = blockIdx.x << 1;
    const int b  = idx0 >> 6;
    const int g0 = idx0 & 63;
    const int tid = threadIdx.x;

    const size_t base = (size_t)b * ((size_t)NFEAT * WH) + (size_t)g0 * (GS * WH);
    const vf4* __restrict__ x0 = (const vf4*)(x + base);
    vf4* __restrict__ o0 = (vf4*)(out + base);

    __shared__ float sW[40];
    if (tid < 40) {
        const int grp = tid / 20, r = tid - grp * 20;
        sW[tid] = wm[(g0 + grp) * 24 + r];
    }
    __syncthreads();

#define APPLY4(W, NW, XIN, O, q)                                               \
    {                                                                          \
        vf4 v0 = XIN[(q)];                                                     \
        vf4 v1 = XIN[(q) + PLANEQ];                                            \
        vf4 v2 = XIN[(q) + 2 * PLANEQ];                                        \
        vf4 v3 = XIN[(q) + 3 * PLANEQ];                                        \
        _Pragma("unroll")                                                      \
        for (int i = 0; i < 4; ++i) {                                          \
            vf4 r;                                                             \
            _Pragma("unroll")                                                  \
            for (int k = 0; k < 4; ++k) {                                      \
                r[k] = fmaf(W[i][0], v0[k],                                    \
                       fmaf(W[i][1], v1[k],                                    \
                       fmaf(W[i][2], v2[k],                                    \
                       fmaf(W[i][3], v3[k], NW[i]))));                         \
            }                                                                  \
            __builtin_nontemporal_store(r, &O[(q) + i * PLANEQ]);              \
        }                                                                      \
    }

    {
        float W[4][4], nw[4];
        #pragma unroll
        for (int i = 0; i < 4; ++i) {
            #pragma unroll
            for (int j = 0; j < 4; ++j) W[i][j] = sW[i * 4 + j];
            nw[i] = sW[16 + i];
        }
        APPLY4(W, nw, x0, o0, tid);
        APPLY4(W, nw, x0, o0, tid + 256);
        APPLY4(W, nw, x0, o0, tid + 512);
        if (tid < PLANEQ - 768) APPLY4(W, nw, x0, o0, tid + 768);
    }
    {
        const vf4* __restrict__ x1 = x0 + GS * PLANEQ;
        vf4* __restrict__ o1 = o0 + GS * PLANEQ;
        float W[4][4], nw[4];
        #pragma unroll
        for (int i = 0; i < 4; ++i) {
            #pragma unroll
            for (int j = 0; j < 4; ++j) W[i][j] = sW[20 + i * 4 + j];
            nw[i] = sW[36 + i];
        }
        APPLY4(W, nw, x1, o1, tid);
        APPLY4(W, nw, x1, o1, tid + 256);
        APPLY4(W, nw, x1, o1, tid + 512);
        if (tid < PLANEQ - 768) APPLY4(W, nw, x1, o1, tid + 768);
    }
#undef APPLY4
}

extern "C" void kernel_launch(void* const* d_in, const int* in_sizes, int n_in,
                              void* d_out, int out_size, void* d_ws, size_t ws_size,
                              hipStream_t stream) {
    const float* x = (const float*)d_in[0];
    float* out = (float*)d_out;

    float* partials = (float*)d_ws;                          // 64*64*16 f = 256 KiB
    float* wm       = partials + (size_t)NG * BATCH * PREC;  // 64*24 f

    wh_reduce<<<BATCH * NG / 2, 256, 0, stream>>>(x, partials);
    wh_eigen<<<NG, 64, 0, stream>>>(partials, wm);
    wh_apply<<<BATCH * NG / 2, 256, 0, stream>>>(x, wm, out);
}

// Round 10
// 110.387 us; speedup vs baseline: 1.6710x; 1.0313x over previous
//
#include <hip/hip_runtime.h>
#include <math.h>

#define BATCH   64
#define NFEAT   256
#define GS      4
#define NG      64
#define WH      3136            // 56*56
#define PLANEQ  784             // WH/4 (float4 quads per channel plane)
#define NTOT    (BATCH*WH)      // 200704 samples per channel
#define EPSV    1e-3
#define PREC    16              // padded floats per partial record

typedef float vf4 __attribute__((ext_vector_type(4)));

// ---------------- Stage 1: per-(b,g) partial sums ----------------
//   q 0..3  = sum x_i ; q 4..13 = sum x_i x_j (i<=j)
// partials[(g*64+b)*16 + q]. Deterministic, no atomics, no fences.
__global__ __launch_bounds__(256) void wh_reduce(const float* __restrict__ x,
                                                 float* __restrict__ partials) {
    const int blk = blockIdx.x;
    const int b = blk >> 6;
    const int g = blk & 63;
    const int tid = threadIdx.x;
    const vf4* __restrict__ xin =
        (const vf4*)(x + (size_t)b * ((size_t)NFEAT * WH) + (size_t)g * (GS * WH));

    // 3 full rounds + 16-thread tail; 12 loads issued back-to-back.
    vf4 a0 = xin[tid];             vf4 a1 = xin[tid + 256];             vf4 a2 = xin[tid + 512];
    vf4 b0 = xin[PLANEQ + tid];    vf4 b1 = xin[PLANEQ + tid + 256];    vf4 b2 = xin[PLANEQ + tid + 512];
    vf4 c0 = xin[2*PLANEQ + tid];  vf4 c1 = xin[2*PLANEQ + tid + 256];  vf4 c2 = xin[2*PLANEQ + tid + 512];
    vf4 d0 = xin[3*PLANEQ + tid];  vf4 d1 = xin[3*PLANEQ + tid + 256];  vf4 d2 = xin[3*PLANEQ + tid + 512];

    float s0=0.f,s1=0.f,s2=0.f,s3=0.f;
    float p0=0.f,p1=0.f,p2=0.f,p3=0.f,p4=0.f,p5=0.f,p6=0.f,p7=0.f,p8=0.f,p9=0.f;

#define ACC4(va, vb, vc, vd)                                         \
    {                                                                \
        _Pragma("unroll")                                            \
        for (int k = 0; k < 4; ++k) {                                \
            float A = (va)[k], B = (vb)[k], C = (vc)[k], D = (vd)[k];\
            s0 += A; s1 += B; s2 += C; s3 += D;                      \
            p0 = fmaf(A, A, p0);  p1 = fmaf(A, B, p1);               \
            p2 = fmaf(A, C, p2);  p3 = fmaf(A, D, p3);               \
            p4 = fmaf(B, B, p4);  p5 = fmaf(B, C, p5);               \
            p6 = fmaf(B, D, p6);  p7 = fmaf(C, C, p7);               \
            p8 = fmaf(C, D, p8);  p9 = fmaf(D, D, p9);               \
        }                                                            \
    }

    ACC4(a0, b0, c0, d0);
    ACC4(a1, b1, c1, d1);
    ACC4(a2, b2, c2, d2);
    if (tid < PLANEQ - 768) {   // 16 tail quads
        vf4 at = xin[768 + tid];
        vf4 bt = xin[PLANEQ + 768 + tid];
        vf4 ct = xin[2*PLANEQ + 768 + tid];
        vf4 dt = xin[3*PLANEQ + 768 + tid];
        ACC4(at, bt, ct, dt);
    }
#undef ACC4

    float vals[14] = {s0,s1,s2,s3,p0,p1,p2,p3,p4,p5,p6,p7,p8,p9};
    #pragma unroll
    for (int q = 0; q < 14; ++q) {
        float v = vals[q];
        #pragma unroll
        for (int off = 32; off > 0; off >>= 1) v += __shfl_down(v, off, 64);
        vals[q] = v;
    }

    __shared__ float lds[4][14];
    const int wave = tid >> 6;
    const int lane = tid & 63;
    if (lane == 0) {
        #pragma unroll
        for (int q = 0; q < 14; ++q) lds[wave][q] = vals[q];
    }
    __syncthreads();
    if (tid < 14) {
        float v = lds[0][tid] + lds[1][tid] + lds[2][tid] + lds[3][tid];
        partials[((size_t)(g * BATCH + b)) * PREC + tid] = v;
    }
}

// ---------------- Stage 2: per-group eigen solve ----------------
// One block per group, 64 threads: butterfly-sum partials in double,
// lane 0 runs tolerance-early-exit Jacobi. Writes wm[g*24]:
//   0..15 = W,  16..19 = -W m,  20..23 = m
__global__ __launch_bounds__(64) void wh_eigen(const float* __restrict__ partials,
                                               float* __restrict__ wm) {
    const int g = blockIdx.x;
    const int b = threadIdx.x;

    const float* base = partials + ((size_t)(g * BATCH + b)) * PREC;
    double acc[14];
    #pragma unroll
    for (int q = 0; q < 14; ++q) acc[q] = (double)base[q];

    #pragma unroll
    for (int off = 32; off > 0; off >>= 1) {
        #pragma unroll
        for (int q = 0; q < 14; ++q) acc[q] += __shfl_xor(acc[q], off, 64);
    }

    if (b != 0) return;

    const double n = (double)NTOT;
    double m[4];
    #pragma unroll
    for (int i = 0; i < 4; ++i) m[i] = acc[i] / n;

    const int pi[10] = {0,0,0,0,1,1,1,2,2,3};
    const int pj[10] = {0,1,2,3,1,2,3,2,3,3};

    double A[4][4];
    #pragma unroll
    for (int t = 0; t < 10; ++t) {
        double cov = acc[4 + t] - n * m[pi[t]] * m[pj[t]];
        double v = (1.0 - EPSV) * cov + ((pi[t] == pj[t]) ? EPSV : 0.0);
        A[pi[t]][pj[t]] = v;
        A[pj[t]][pi[t]] = v;
    }

    double V[4][4] = {{1,0,0,0},{0,1,0,0},{0,0,1,0},{0,0,0,1}};

    const double tr = A[0][0] + A[1][1] + A[2][2] + A[3][3];
    const double tol = 1e-26 * tr * tr + 1e-300;

    const int rp[6] = {0,0,0,1,1,2};
    const int rq[6] = {1,2,3,2,3,3};

    for (int sweep = 0; sweep < 10; ++sweep) {
        double off = 0.0;
        #pragma unroll
        for (int t = 0; t < 6; ++t) off += A[rp[t]][rq[t]] * A[rp[t]][rq[t]];
        if (off < tol) break;

        #pragma unroll
        for (int t = 0; t < 6; ++t) {
            const int p = rp[t], q = rq[t];
            double apq = A[p][q];
            if (apq * apq < 1e-60) continue;
            double theta = (A[q][q] - A[p][p]) / (2.0 * apq);
            double tt = ((theta >= 0.0) ? 1.0 : -1.0) /
                        (fabs(theta) + sqrt(theta * theta + 1.0));
            double c = 1.0 / sqrt(tt * tt + 1.0);
            double s = tt * c;
            #pragma unroll
            for (int k = 0; k < 4; ++k) {
                double akp = A[k][p], akq = A[k][q];
                A[k][p] = c * akp - s * akq;
                A[k][q] = s * akp + c * akq;
            }
            #pragma unroll
            for (int k = 0; k < 4; ++k) {
                double apk = A[p][k], aqk = A[q][k];
                A[p][k] = c * apk - s * aqk;
                A[q][k] = s * apk + c * aqk;
            }
            #pragma unroll
            for (int k = 0; k < 4; ++k) {
                double vkp = V[k][p], vkq = V[k][q];
                V[k][p] = c * vkp - s * vkq;
                V[k][q] = s * vkp + c * vkq;
            }
        }
    }

    double isq[4];
    #pragma unroll
    for (int k = 0; k < 4; ++k) isq[k] = 1.0 / sqrt(A[k][k] + EPSV);

    float* wo = wm + g * 24;
    double Wd[4][4];
    #pragma unroll
    for (int i = 0; i < 4; ++i) {
        #pragma unroll
        for (int j = 0; j < 4; ++j) {
            double w = 0.0;
            #pragma unroll
            for (int k = 0; k < 4; ++k) w += V[i][k] * V[j][k] * isq[k];
            Wd[i][j] = w;
            wo[i * 4 + j] = (float)w;
        }
    }
    #pragma unroll
    for (int i = 0; i < 4; ++i) {
        double wmI = Wd[i][0]*m[0] + Wd[i][1]*m[1] + Wd[i][2]*m[2] + Wd[i][3]*m[3];
        wo[16 + i] = (float)(-wmI);   // -W m
        wo[20 + i] = (float)m[i];
    }
}

// ---------------- Stage 3: apply out_i = sum_j W_ij x_j + (-W m)_i ----
// Plain loads on x (R7: NT loads regress), NT stores on out (R5 best).
__global__ __launch_bounds__(256) void wh_apply(const float* __restrict__ x,
                                                const float* __restrict__ wm,
                                                float* __restrict__ out) {
    const int blk = blockIdx.x;
    const int b = blk >> 6;
    const int g = blk & 63;
    const int tid = threadIdx.x;

    __shared__ float sW[20];
    if (tid < 20) sW[tid] = wm[g * 24 + tid];
    __syncthreads();

    float W[4][4], nwm[4];
    #pragma unroll
    for (int i = 0; i < 4; ++i) {
        #pragma unroll
        for (int j = 0; j < 4; ++j) W[i][j] = sW[i * 4 + j];
        nwm[i] = sW[16 + i];
    }

    const size_t off = (size_t)b * ((size_t)NFEAT * WH) + (size_t)g * (GS * WH);
    const vf4* __restrict__ xin = (const vf4*)(x + off);
    vf4* __restrict__ o = (vf4*)(out + off);

#define APPLY4(q)                                                              \
    {                                                                          \
        vf4 v0 = xin[(q)];                                                     \
        vf4 v1 = xin[(q) + PLANEQ];                                            \
        vf4 v2 = xin[(q) + 2 * PLANEQ];                                        \
        vf4 v3 = xin[(q) + 3 * PLANEQ];                                        \
        _Pragma("unroll")                                                      \
        for (int i = 0; i < 4; ++i) {                                          \
            vf4 r;                                                             \
            _Pragma("unroll")                                                  \
            for (int k = 0; k < 4; ++k) {                                      \
                r[k] = fmaf(W[i][0], v0[k],                                    \
                       fmaf(W[i][1], v1[k],                                    \
                       fmaf(W[i][2], v2[k],                                    \
                       fmaf(W[i][3], v3[k], nwm[i]))));                        \
            }                                                                  \
            __builtin_nontemporal_store(r, &o[(q) + i * PLANEQ]);              \
        }                                                                      \
    }

    APPLY4(tid);
    APPLY4(tid + 256);
    APPLY4(tid + 512);
    if (tid < PLANEQ - 768) APPLY4(tid + 768);
#undef APPLY4
}

extern "C" void kernel_launch(void* const* d_in, const int* in_sizes, int n_in,
                              void* d_out, int out_size, void* d_ws, size_t ws_size,
                              hipStream_t stream) {
    const float* x = (const float*)d_in[0];
    float* out = (float*)d_out;

    float* partials = (float*)d_ws;                          // 64*64*16 f = 256 KiB
    float* wm       = partials + (size_t)NG * BATCH * PREC;  // 64*24 f

    wh_reduce<<<BATCH * NG, 256, 0, stream>>>(x, partials);
    wh_eigen<<<NG, 64, 0, stream>>>(partials, wm);
    wh_apply<<<BATCH * NG, 256, 0, stream>>>(x, wm, out);
}